// Round 18
// baseline (218.402 us; speedup 1.0000x reference)
//
#include <hip/hip_runtime.h>

using short8 = __attribute__((ext_vector_type(8))) short;
using f32x4  = __attribute__((ext_vector_type(4))) float;

#define SCALE_Q 0.17677669529663687f   // 32^-0.5
#define NCHUNK 16

__device__ __forceinline__ unsigned short f2bf(float f) {
  unsigned u = __float_as_uint(f);
  return (unsigned short)((u + 0x7FFFu + ((u >> 16) & 1u)) >> 16);  // RNE
}
__device__ __forceinline__ float bf2f(unsigned h) { return __uint_as_float(h << 16); }

__device__ __forceinline__ void bf8_to_f(uint4 r, float* o) {
  o[0] = bf2f(r.x & 0xffffu); o[1] = bf2f(r.x >> 16);
  o[2] = bf2f(r.y & 0xffffu); o[3] = bf2f(r.y >> 16);
  o[4] = bf2f(r.z & 0xffffu); o[5] = bf2f(r.z >> 16);
  o[6] = bf2f(r.w & 0xffffu); o[7] = bf2f(r.w >> 16);
}

// ---------------- prep: x fp32 -> bf16; transpose-convert weights ----------------
__global__ __launch_bounds__(256) void prep_kernel(
    const float* __restrict__ x, const float* __restrict__ wqkv, const float* __restrict__ wout,
    unsigned short* __restrict__ xb, unsigned short* __restrict__ wqkvT,
    unsigned short* __restrict__ woutT) {
  const int blk = blockIdx.x;
  if (blk < 16384) {
    const size_t i = ((size_t)blk * 256 + threadIdx.x) * 4;
    const float4 v = *(const float4*)(x + i);
    *(ushort4*)(xb + i) = make_ushort4(f2bf(v.x), f2bf(v.y), f2bf(v.z), f2bf(v.w));
  } else if (blk < 16384 + 768) {
    const int n = blk - 16384, k = threadIdx.x;            // wqkvT[n][k] = wqkv[k][n]
    wqkvT[n * 256 + k] = f2bf(wqkv[(size_t)k * 768 + n]);
  } else {
    const int c = blk - 16384 - 768, f = threadIdx.x;      // woutT[c][f] = wout[f][c]
    woutT[c * 256 + f] = f2bf(wout[(size_t)f * 256 + c]);
  }
}

// ---------------- gemm_qkv: LDS-FREE — fragments loaded global->VGPR directly ----
// Rationale (R17 analysis): the LDS round-trip was the bottleneck pipe (96 KB/iter
// per CU = 1130 cyc vs 621 cyc MFMA), and with K=256 the whole A panel (64 KB) and
// B (384 KB) are L2-resident. Lane (fr,hi) loads A[row+fr][hi*8..+8] as one b128:
// a wave covers 16 rows x 64 B = 16 FULL cache lines. No LDS, no barriers;
// 1-deep fragment prefetch for ILP; TLP from ~3 waves/SIMD hides L2 latency.
// MFMA operands SWAPPED (R8-verified): lane (fr,hi) reg r holds
// D[r0 + mi*16 + fr][cb + nj*16 + hi*4 + r] -> packed stores, 2-shfl q-softmax.
// Bijective XCD chunk remap: same-bm strips co-XCD (A panel L2-hot).
// bn 0..1 -> fused q-softmax into QS; bn 2..3 -> k, bn 4..5 -> v into KV[.][512].
__global__ __launch_bounds__(256) void gemm_qkv(
    const unsigned short* __restrict__ A, const unsigned short* __restrict__ BT,
    unsigned short* __restrict__ KV, unsigned short* __restrict__ QS, int K) {
  const int cpx = (int)gridDim.x >> 3;
  const int lin = ((int)blockIdx.x & 7) * cpx + ((int)blockIdx.x >> 3);
  const int bn = lin % 6, bm = lin / 6;
  const int tid = threadIdx.x, lane = tid & 63, wid = tid >> 6;
  const int wr = wid >> 1, wc = wid & 1;
  const int fr = lane & 15, hi = lane >> 4;
  f32x4 acc[4][4] = {};

  // fragment base pointers (per-lane): row = strip + mi*16 + fr, k-chunk = hi*8
  const unsigned short* ApA = A  + ((size_t)bm * 128 + wr * 64 + fr) * K + hi * 8;
  const unsigned short* ApB = BT + ((size_t)bn * 128 + wc * 64 + fr) * K + hi * 8;

  short8 ac[4], bc[4], an[4], bnx[4];
#pragma unroll
  for (int i = 0; i < 4; ++i) {
    ac[i] = *(const short8*)(ApA + (size_t)i * 16 * K);
    bc[i] = *(const short8*)(ApB + (size_t)i * 16 * K);
  }
  const int ktiles = K >> 5;
  for (int t = 0; t < ktiles; ++t) {
    if (t + 1 < ktiles) {                 // prefetch next frags (fly under MFMA)
      const int kt = (t + 1) * 32;
#pragma unroll
      for (int i = 0; i < 4; ++i) {
        an[i]  = *(const short8*)(ApA + (size_t)i * 16 * K + kt);
        bnx[i] = *(const short8*)(ApB + (size_t)i * 16 * K + kt);
      }
    }
#pragma unroll
    for (int mi = 0; mi < 4; ++mi)
#pragma unroll
      for (int nj = 0; nj < 4; ++nj)  // swapped operands
        acc[mi][nj] = __builtin_amdgcn_mfma_f32_16x16x32_bf16(bc[nj], ac[mi], acc[mi][nj], 0, 0, 0);
#pragma unroll
    for (int i = 0; i < 4; ++i) { ac[i] = an[i]; bc[i] = bnx[i]; }
  }

  const size_t r0 = (size_t)bm * 128 + wr * 64;
  if (bn < 2) {
    // q strips: per (row, head p) softmax over d=32. Lane holds 8 of the 32
    // d-values; reduce across hi groups with 2 shfl_xor (16, 32).
    const int c0 = bn * 128 + wc * 64;
#pragma unroll
    for (int mi = 0; mi < 4; ++mi) {
      const size_t row = r0 + mi * 16 + fr;
#pragma unroll
      for (int p = 0; p < 2; ++p) {
        const f32x4 a0 = acc[mi][2 * p], a1 = acc[mi][2 * p + 1];
        float mx = fmaxf(fmaxf(fmaxf(a0[0], a0[1]), fmaxf(a0[2], a0[3])),
                         fmaxf(fmaxf(a1[0], a1[1]), fmaxf(a1[2], a1[3])));
        mx = fmaxf(mx, __shfl_xor(mx, 16, 64));
        mx = fmaxf(mx, __shfl_xor(mx, 32, 64));
        float e0[4], e1[4], s = 0.f;
#pragma unroll
        for (int r = 0; r < 4; ++r) {
          e0[r] = __expf(a0[r] - mx); e1[r] = __expf(a1[r] - mx);
          s += e0[r] + e1[r];
        }
        s += __shfl_xor(s, 16, 64);
        s += __shfl_xor(s, 32, 64);
        const float inv = SCALE_Q / s;
        unsigned short* qp = QS + row * 256 + c0 + p * 32 + hi * 4;
        *(ushort4*)(qp)      = make_ushort4(f2bf(e0[0]*inv), f2bf(e0[1]*inv), f2bf(e0[2]*inv), f2bf(e0[3]*inv));
        *(ushort4*)(qp + 16) = make_ushort4(f2bf(e1[0]*inv), f2bf(e1[1]*inv), f2bf(e1[2]*inv), f2bf(e1[3]*inv));
      }
    }
    return;
  }
  const int colbase = (bn - 2) * 128 + wc * 64;   // kv row = 512 cols (k 0..255, v 256+)
#pragma unroll
  for (int mi = 0; mi < 4; ++mi) {
    const size_t row = r0 + mi * 16 + fr;
#pragma unroll
    for (int nj = 0; nj < 4; ++nj) {
      const int col0 = colbase + nj * 16 + hi * 4;
      const f32x4 v = acc[mi][nj];
      *(ushort4*)(KV + row * 512 + col0) =
          make_ushort4(f2bf(v[0]), f2bf(v[1]), f2bf(v[2]), f2bf(v[3]));
    }
  }
}

// ---------------- gemm_out: LDS-free, batched, fp32 out --------------------------
// 1D grid 1024, XCD-chunked with bn fastest (qs A-tile L2 reuse across bn).
__global__ __launch_bounds__(256) void gemm_out(
    const unsigned short* __restrict__ A, const unsigned short* __restrict__ BT,
    float* __restrict__ D, int K) {
  const int cpx = (int)gridDim.x >> 3;
  const int lin = ((int)blockIdx.x & 7) * cpx + ((int)blockIdx.x >> 3);
  const int bn = lin & 1, bm = (lin >> 1) & 31, bz = lin >> 6;
  const int tid = threadIdx.x, lane = tid & 63, wid = tid >> 6;
  const int wr = wid >> 1, wc = wid & 1;
  const int fr = lane & 15, hi = lane >> 4;
  f32x4 acc[4][4] = {};
  const size_t abase = (size_t)bz * 4096 * 256 + (size_t)bm * 128 * K;
  const size_t bbase = (size_t)bz * 256 * 256 + (size_t)bn * 128 * K;

  const unsigned short* ApA = A  + abase + ((size_t)wr * 64 + fr) * K + hi * 8;
  const unsigned short* ApB = BT + bbase + ((size_t)wc * 64 + fr) * K + hi * 8;

  short8 ac[4], bc[4], an[4], bnx[4];
#pragma unroll
  for (int i = 0; i < 4; ++i) {
    ac[i] = *(const short8*)(ApA + (size_t)i * 16 * K);
    bc[i] = *(const short8*)(ApB + (size_t)i * 16 * K);
  }
  const int ktiles = K >> 5;
  for (int t = 0; t < ktiles; ++t) {
    if (t + 1 < ktiles) {
      const int kt = (t + 1) * 32;
#pragma unroll
      for (int i = 0; i < 4; ++i) {
        an[i]  = *(const short8*)(ApA + (size_t)i * 16 * K + kt);
        bnx[i] = *(const short8*)(ApB + (size_t)i * 16 * K + kt);
      }
    }
#pragma unroll
    for (int mi = 0; mi < 4; ++mi)
#pragma unroll
      for (int nj = 0; nj < 4; ++nj)
        acc[mi][nj] = __builtin_amdgcn_mfma_f32_16x16x32_bf16(bc[nj], ac[mi], acc[mi][nj], 0, 0, 0);
#pragma unroll
    for (int i = 0; i < 4; ++i) { ac[i] = an[i]; bc[i] = bnx[i]; }
  }

  const size_t r0 = (size_t)bm * 128 + wr * 64;
  const int colbase = bn * 128 + wc * 64;
  float* Dz = D + (size_t)bz * 4096 * 256;
#pragma unroll
  for (int mi = 0; mi < 4; ++mi) {
    const size_t row = r0 + mi * 16 + fr;
#pragma unroll
    for (int nj = 0; nj < 4; ++nj) {
      const f32x4 v = acc[mi][nj];
      *(float4*)(Dz + row * 256 + colbase + nj * 16 + hi * 4) =
          make_float4(v[0], v[1], v[2], v[3]);
    }
  }
}

// ---------------- ctx partials: per (b,h,chunk): sum_n exp(k[d,n])*v[e,n] ---------
// kv layout [65536][512]: k at cols 0..255, v at 256..511.
__global__ __launch_bounds__(256) void ctx_part_kernel(const unsigned short* __restrict__ kv,
                                                       float* __restrict__ part,
                                                       float* __restrict__ spart) {
  const int blk = blockIdx.x;
  const int bh = blk >> 4, chunk = blk & 15;
  const int b = bh >> 3, h = bh & 7;
  const int tid = threadIdx.x, d = tid & 31, g = tid >> 5;
  const unsigned short* kbase =
      kv + (size_t)b * 4096 * 512 + h * 32 + (size_t)chunk * 256 * 512;
  const unsigned short* vbase = kbase + 256;

  __shared__ float ek[64][36], vv[64][36];
  float a0 = 0.f, a1 = 0.f, a2 = 0.f, a3 = 0.f, ssum = 0.f;
  const int e0 = g * 4;
  const int sn = tid >> 2, sc = (tid & 3) * 8;
  const unsigned short* kp0 = kbase + (size_t)sn * 512 + sc;
  const unsigned short* vp0 = vbase + (size_t)sn * 512 + sc;
  uint4 kr = *(const uint4*)kp0;
  uint4 vr = *(const uint4*)vp0;
  for (int n0 = 0; n0 < 256; n0 += 64) {
    float kf[8], vf[8];
    bf8_to_f(kr, kf); bf8_to_f(vr, vf);
    uint4 krn = kr, vrn = vr;
    if (n0 + 64 < 256) {
      krn = *(const uint4*)(kp0 + (size_t)(n0 + 64) * 512);
      vrn = *(const uint4*)(vp0 + (size_t)(n0 + 64) * 512);
    }
#pragma unroll
    for (int j = 0; j < 8; ++j) { ek[sn][sc + j] = __expf(kf[j]); vv[sn][sc + j] = vf[j]; }
    __syncthreads();
#pragma unroll 8
    for (int i = 0; i < 64; ++i) {
      const float kd = ek[i][d];
      const float4 v4 = *(const float4*)&vv[i][e0];
      ssum += kd;
      a0 += kd * v4.x; a1 += kd * v4.y; a2 += kd * v4.z; a3 += kd * v4.w;
    }
    __syncthreads();
    kr = krn; vr = vrn;
  }
  float* pp = part + ((size_t)chunk * 128 + bh) * 1024 + d * 32 + e0;
  pp[0] = a0; pp[1] = a1; pp[2] = a2; pp[3] = a3;
  if (g == 0) spart[((size_t)chunk * 128 + bh) * 32 + d] = ssum;
}

// ---------------- ctx combine: ctx[d][e] = sum_c part / sum_c spart ---------------
__global__ __launch_bounds__(256) void ctx_combine_kernel(const float* __restrict__ part,
                                                          const float* __restrict__ spart,
                                                          float* __restrict__ ctx) {
  const int bh = blockIdx.x, tid = threadIdx.x;
  __shared__ float sinv[32];
  if (tid < 32) {
    float s = 0.f;
#pragma unroll
    for (int c = 0; c < NCHUNK; ++c) s += spart[((size_t)c * 128 + bh) * 32 + tid];
    sinv[tid] = 1.0f / s;
  }
  __syncthreads();
  float4 acc = make_float4(0.f, 0.f, 0.f, 0.f);
#pragma unroll
  for (int c = 0; c < NCHUNK; ++c) {
    const float4 p = *(const float4*)(part + ((size_t)c * 128 + bh) * 1024 + tid * 4);
    acc.x += p.x; acc.y += p.y; acc.z += p.z; acc.w += p.w;
  }
  const float si = sinv[tid >> 3];  // d = (tid*4)>>5
  float4* cp = (float4*)(ctx + (size_t)bh * 1024 + tid * 4);
  *cp = make_float4(acc.x * si, acc.y * si, acc.z * si, acc.w * si);
}

// ---------------- w2: W2T[b][c][(h,d)] = sum_e ctx[b,h,d,e] * woutT[c][(h,e)] -----
__global__ __launch_bounds__(256) void w2_kernel(const float* __restrict__ ctx,
                                                 const unsigned short* __restrict__ woutT,
                                                 unsigned short* __restrict__ W2T) {
  const int b = blockIdx.x >> 4, cg = blockIdx.x & 15;
  const int tid = threadIdx.x;
  __shared__ float cs[8 * 32 * 32];  // ctx[b]: 8 heads x 32d x 32e = 32 KB
  {
    const float4* src = (const float4*)(ctx + (size_t)b * 8192);
    float4* dst = (float4*)cs;
#pragma unroll
    for (int i = 0; i < 8; ++i) dst[tid + i * 256] = src[tid + i * 256];
  }
  __syncthreads();
  const int c = cg * 16 + (tid >> 4), chunk = tid & 15;
  const int h = chunk >> 1, d0 = (chunk & 1) * 16;
  float wf[32];
  {
    const uint4* wp = (const uint4*)(woutT + (size_t)c * 256 + h * 32);
    bf8_to_f(wp[0], wf + 0); bf8_to_f(wp[1], wf + 8);
    bf8_to_f(wp[2], wf + 16); bf8_to_f(wp[3], wf + 24);
  }
  unsigned short o[16];
#pragma unroll
  for (int dd = 0; dd < 16; ++dd) {
    const float* cp = cs + h * 1024 + (d0 + dd) * 32;
    float acc = 0.f;
#pragma unroll
    for (int e = 0; e < 32; ++e) acc += cp[e] * wf[e];
    o[dd] = f2bf(acc);
  }
  uint4* op = (uint4*)(W2T + ((size_t)b * 256 + c) * 256 + chunk * 16);
  op[0] = make_uint4((unsigned)o[0] | ((unsigned)o[1] << 16), (unsigned)o[2] | ((unsigned)o[3] << 16),
                     (unsigned)o[4] | ((unsigned)o[5] << 16), (unsigned)o[6] | ((unsigned)o[7] << 16));
  op[1] = make_uint4((unsigned)o[8] | ((unsigned)o[9] << 16), (unsigned)o[10] | ((unsigned)o[11] << 16),
                     (unsigned)o[12] | ((unsigned)o[13] << 16), (unsigned)o[14] | ((unsigned)o[15] << 16));
}

extern "C" void kernel_launch(void* const* d_in, const int* in_sizes, int n_in,
                              void* d_out, int out_size, void* d_ws, size_t ws_size,
                              hipStream_t stream) {
  const float* x     = (const float*)d_in[0];  // [16,64,64,256] = [65536][256]
  const float* wqkv  = (const float*)d_in[1];  // [256,768]
  const float* wout  = (const float*)d_in[2];  // [256,256]
  float* out = (float*)d_out;                  // [65536,256] fp32

  char* ws = (char*)d_ws;
  unsigned short* xb    = (unsigned short*)(ws);                 // 32 MB (dead after gemm_qkv)
  unsigned short* wqkvT = (unsigned short*)(ws + 33554432);      // 384 KB
  unsigned short* woutT = (unsigned short*)(ws + 33947648);      // 128 KB
  unsigned short* kv    = (unsigned short*)(ws + 34078720);      // 64 MB [65536][512]
  float*          ctx   = (float*)        (ws + 101187584);      // 512 KB [128][32][32]
  unsigned short* qs    = (unsigned short*)(ws + 101711872);     // 32 MB [65536][256]
  // reuse xb region (dead after gemm_qkv):
  float*          part  = (float*)(ws);                          // 8 MB [16][128][1024]
  float*          spart = (float*)(ws + 8388608);                // 256 KB [16][128][32]
  unsigned short* W2T   = (unsigned short*)(ws + 12582912);      // 2 MB [16][256][256]

  prep_kernel<<<16384 + 768 + 256, 256, 0, stream>>>(x, wqkv, wout, xb, wqkvT, woutT);
  // gemm1: 6 bn strips (q 0..1 -> softmax -> qs; k 2..3 / v 4..5 -> kv[.][512]).
  // 1D grid 3072, XCD-swizzled.
  gemm_qkv<<<3072, 256, 0, stream>>>(xb, wqkvT, kv, qs, 256);
  ctx_part_kernel<<<2048, 256, 0, stream>>>(kv, part, spart);
  ctx_combine_kernel<<<128, 256, 0, stream>>>(part, spart, ctx);
  w2_kernel<<<256, 256, 0, stream>>>(ctx, woutT, W2T);
  // gemm2: batched z=16, M=4096, N=256, K=256; 1D grid 1024, XCD-chunked (bn fast).
  gemm_out<<<1024, 256, 0, stream>>>(qs, W2T, out, 256);
}

// Round 19
// 156.428 us; speedup vs baseline: 1.3962x; 1.3962x over previous
//
#include <hip/hip_runtime.h>

using short8 = __attribute__((ext_vector_type(8))) short;
using f32x4  = __attribute__((ext_vector_type(4))) float;

#define SCALE_Q 0.17677669529663687f   // 32^-0.5
#define NCHUNK 16

__device__ __forceinline__ unsigned short f2bf(float f) {
  unsigned u = __float_as_uint(f);
  return (unsigned short)((u + 0x7FFFu + ((u >> 16) & 1u)) >> 16);  // RNE
}
__device__ __forceinline__ float bf2f(unsigned h) { return __uint_as_float(h << 16); }

__device__ __forceinline__ void bf8_to_f(uint4 r, float* o) {
  o[0] = bf2f(r.x & 0xffffu); o[1] = bf2f(r.x >> 16);
  o[2] = bf2f(r.y & 0xffffu); o[3] = bf2f(r.y >> 16);
  o[4] = bf2f(r.z & 0xffffu); o[5] = bf2f(r.z >> 16);
  o[6] = bf2f(r.w & 0xffffu); o[7] = bf2f(r.w >> 16);
}

// ---------------- prep: x fp32 -> bf16 (grid-stride); transpose-convert weights --
__global__ __launch_bounds__(256) void prep_kernel(
    const float* __restrict__ x, const float* __restrict__ wqkv, const float* __restrict__ wout,
    unsigned short* __restrict__ xb, unsigned short* __restrict__ wqkvT,
    unsigned short* __restrict__ woutT) {
  const int blk = blockIdx.x;
  if (blk < 2048) {
    // x: 16.78M elems = 4.19M float4 chunks; 2048 blocks x 256 thr x 8 chunks
    size_t idx = (size_t)blk * 256 + threadIdx.x;
#pragma unroll
    for (int it = 0; it < 8; ++it, idx += 2048 * 256) {
      const float4 v = *(const float4*)(x + idx * 4);
      *(ushort4*)(xb + idx * 4) = make_ushort4(f2bf(v.x), f2bf(v.y), f2bf(v.z), f2bf(v.w));
    }
  } else if (blk < 2048 + 768) {
    const int n = blk - 2048, k = threadIdx.x;             // wqkvT[n][k] = wqkv[k][n]
    wqkvT[n * 256 + k] = f2bf(wqkv[(size_t)k * 768 + n]);
  } else {
    const int c = blk - 2048 - 768, f = threadIdx.x;       // woutT[c][f] = wout[f][c]
    woutT[c * 256 + f] = f2bf(wout[(size_t)f * 256 + c]);
  }
}

// ---------------- gemm_qkv: R14 dbuf skeleton (measured best: 65.4 us) -----------
// qkv = xb[65536][256] * wqkvT[768][256]^T. 128x128 tile, BK=32, padded LDS x2,
// 4 waves (2x2), 4x4 frags of 16x16x32, rolled loop (VGPR 76). Pipeline per iter:
//   issue global loads(t+1) -> ds_read+MFMA(t) -> ds_write(t+1 -> buf^1) -> barrier.
// MFMA operands SWAPPED (R8-verified): lane (fr,hi) reg r holds
// D[r0 + mi*16 + fr][cb + nj*16 + hi*4 + r] -> packed stores, 2-shfl q-softmax.
// Bijective XCD chunk remap: same-bm strips co-XCD (FETCH ~18 MB).
// bn 0..1 -> fused q-softmax into QS; bn 2..3 -> k, bn 4..5 -> v into KV[.][512].
// launch_bounds(256,4): 4 waves/EU target (LDS 40 KB and VGPR 76 allow 4 blk/CU).
__global__ __launch_bounds__(256, 4) void gemm_qkv(
    const unsigned short* __restrict__ A, const unsigned short* __restrict__ BT,
    unsigned short* __restrict__ KV, unsigned short* __restrict__ QS, int K) {
  __shared__ unsigned short As[2][128][40];
  __shared__ unsigned short Bs[2][128][40];
  const int cpx = (int)gridDim.x >> 3;
  const int lin = ((int)blockIdx.x & 7) * cpx + ((int)blockIdx.x >> 3);
  const int bn = lin % 6, bm = lin / 6;
  const int tid = threadIdx.x, lane = tid & 63, wid = tid >> 6;
  const int wr = wid >> 1, wc = wid & 1;
  const int fr = lane & 15, hi = lane >> 4, fk = hi * 8;
  f32x4 acc[4][4] = {};
  const size_t abase = (size_t)bm * 128 * K;
  const size_t bbase = (size_t)bn * 128 * K;

  const int srow = tid >> 2, skc = (tid & 3) * 8;   // 2 chunks/thread per matrix
  uint4 ra0, ra1, rb0, rb1;
  const unsigned short* Ap = A + abase + (size_t)srow * K + skc;
  const unsigned short* Bp = BT + bbase + (size_t)srow * K + skc;

  // prologue: tile 0
  ra0 = *(const uint4*)(Ap);            ra1 = *(const uint4*)(Ap + (size_t)64 * K);
  rb0 = *(const uint4*)(Bp);            rb1 = *(const uint4*)(Bp + (size_t)64 * K);
  *(uint4*)&As[0][srow][skc] = ra0;     *(uint4*)&As[0][srow + 64][skc] = ra1;
  *(uint4*)&Bs[0][srow][skc] = rb0;     *(uint4*)&Bs[0][srow + 64][skc] = rb1;
  __syncthreads();

  const int ktiles = K >> 5;
  int cur = 0;
  for (int t = 0; t < ktiles; ++t) {
    if (t + 1 < ktiles) {                 // issue next tile's loads (fly under MFMA)
      const int kt = (t + 1) * 32;
      ra0 = *(const uint4*)(Ap + kt);     ra1 = *(const uint4*)(Ap + (size_t)64 * K + kt);
      rb0 = *(const uint4*)(Bp + kt);     rb1 = *(const uint4*)(Bp + (size_t)64 * K + kt);
    }
    short8 af[4], bfv[4];
#pragma unroll
    for (int i = 0; i < 4; ++i) {
      af[i]  = *(const short8*)&As[cur][wr * 64 + i * 16 + fr][fk];
      bfv[i] = *(const short8*)&Bs[cur][wc * 64 + i * 16 + fr][fk];
    }
#pragma unroll
    for (int mi = 0; mi < 4; ++mi)
#pragma unroll
      for (int nj = 0; nj < 4; ++nj)  // swapped operands
        acc[mi][nj] = __builtin_amdgcn_mfma_f32_16x16x32_bf16(bfv[nj], af[mi], acc[mi][nj], 0, 0, 0);
    if (t + 1 < ktiles) {                 // write-late into the other buffer
      *(uint4*)&As[cur ^ 1][srow][skc] = ra0;  *(uint4*)&As[cur ^ 1][srow + 64][skc] = ra1;
      *(uint4*)&Bs[cur ^ 1][srow][skc] = rb0;  *(uint4*)&Bs[cur ^ 1][srow + 64][skc] = rb1;
    }
    __syncthreads();                      // single barrier per iteration
    cur ^= 1;
  }

  const size_t r0 = (size_t)bm * 128 + wr * 64;
  if (bn < 2) {
    // q strips: per (row, head p) softmax over d=32. Lane holds 8 of the 32
    // d-values; reduce across hi groups with 2 shfl_xor (16, 32).
    const int c0 = bn * 128 + wc * 64;
#pragma unroll
    for (int mi = 0; mi < 4; ++mi) {
      const size_t row = r0 + mi * 16 + fr;
#pragma unroll
      for (int p = 0; p < 2; ++p) {
        const f32x4 a0 = acc[mi][2 * p], a1 = acc[mi][2 * p + 1];
        float mx = fmaxf(fmaxf(fmaxf(a0[0], a0[1]), fmaxf(a0[2], a0[3])),
                         fmaxf(fmaxf(a1[0], a1[1]), fmaxf(a1[2], a1[3])));
        mx = fmaxf(mx, __shfl_xor(mx, 16, 64));
        mx = fmaxf(mx, __shfl_xor(mx, 32, 64));
        float e0[4], e1[4], s = 0.f;
#pragma unroll
        for (int r = 0; r < 4; ++r) {
          e0[r] = __expf(a0[r] - mx); e1[r] = __expf(a1[r] - mx);
          s += e0[r] + e1[r];
        }
        s += __shfl_xor(s, 16, 64);
        s += __shfl_xor(s, 32, 64);
        const float inv = SCALE_Q / s;
        unsigned short* qp = QS + row * 256 + c0 + p * 32 + hi * 4;
        *(ushort4*)(qp)      = make_ushort4(f2bf(e0[0]*inv), f2bf(e0[1]*inv), f2bf(e0[2]*inv), f2bf(e0[3]*inv));
        *(ushort4*)(qp + 16) = make_ushort4(f2bf(e1[0]*inv), f2bf(e1[1]*inv), f2bf(e1[2]*inv), f2bf(e1[3]*inv));
      }
    }
    return;
  }
  const int colbase = (bn - 2) * 128 + wc * 64;   // kv row = 512 cols (k 0..255, v 256+)
#pragma unroll
  for (int mi = 0; mi < 4; ++mi) {
    const size_t row = r0 + mi * 16 + fr;
#pragma unroll
    for (int nj = 0; nj < 4; ++nj) {
      const int col0 = colbase + nj * 16 + hi * 4;
      const f32x4 v = acc[mi][nj];
      *(ushort4*)(KV + row * 512 + col0) =
          make_ushort4(f2bf(v[0]), f2bf(v[1]), f2bf(v[2]), f2bf(v[3]));
    }
  }
}

// ---------------- gemm_out: R16 version -------------------------------------------
// 1-deep dbuf body, batched, fp32 out. 1D grid 1024, XCD-chunked with bn fastest:
// both bn strips of one (bm,z) run adjacently on the same XCD -> 2nd qs A-tile
// read is an L2 hit.
__global__ __launch_bounds__(256, 4) void gemm_out(
    const unsigned short* __restrict__ A, const unsigned short* __restrict__ BT,
    float* __restrict__ D, int K) {
  __shared__ unsigned short As[2][128][40];
  __shared__ unsigned short Bs[2][128][40];
  const int cpx = (int)gridDim.x >> 3;
  const int lin = ((int)blockIdx.x & 7) * cpx + ((int)blockIdx.x >> 3);
  const int bn = lin & 1, bm = (lin >> 1) & 31, bz = lin >> 6;
  const int tid = threadIdx.x, lane = tid & 63, wid = tid >> 6;
  const int wr = wid >> 1, wc = wid & 1;
  const int fr = lane & 15, hi = lane >> 4, fk = hi * 8;
  f32x4 acc[4][4] = {};
  const size_t abase = (size_t)bz * 4096 * 256 + (size_t)bm * 128 * K;
  const size_t bbase = (size_t)bz * 256 * 256 + (size_t)bn * 128 * K;

  const int srow = tid >> 2, skc = (tid & 3) * 8;
  uint4 ra0, ra1, rb0, rb1;
  const unsigned short* Ap = A + abase + (size_t)srow * K + skc;
  const unsigned short* Bp = BT + bbase + (size_t)srow * K + skc;

  ra0 = *(const uint4*)(Ap);            ra1 = *(const uint4*)(Ap + (size_t)64 * K);
  rb0 = *(const uint4*)(Bp);            rb1 = *(const uint4*)(Bp + (size_t)64 * K);
  *(uint4*)&As[0][srow][skc] = ra0;     *(uint4*)&As[0][srow + 64][skc] = ra1;
  *(uint4*)&Bs[0][srow][skc] = rb0;     *(uint4*)&Bs[0][srow + 64][skc] = rb1;
  __syncthreads();

  const int ktiles = K >> 5;
  int cur = 0;
  for (int t = 0; t < ktiles; ++t) {
    if (t + 1 < ktiles) {
      const int kt = (t + 1) * 32;
      ra0 = *(const uint4*)(Ap + kt);     ra1 = *(const uint4*)(Ap + (size_t)64 * K + kt);
      rb0 = *(const uint4*)(Bp + kt);     rb1 = *(const uint4*)(Bp + (size_t)64 * K + kt);
    }
    short8 af[4], bfv[4];
#pragma unroll
    for (int i = 0; i < 4; ++i) {
      af[i]  = *(const short8*)&As[cur][wr * 64 + i * 16 + fr][fk];
      bfv[i] = *(const short8*)&Bs[cur][wc * 64 + i * 16 + fr][fk];
    }
#pragma unroll
    for (int mi = 0; mi < 4; ++mi)
#pragma unroll
      for (int nj = 0; nj < 4; ++nj)
        acc[mi][nj] = __builtin_amdgcn_mfma_f32_16x16x32_bf16(bfv[nj], af[mi], acc[mi][nj], 0, 0, 0);
    if (t + 1 < ktiles) {
      *(uint4*)&As[cur ^ 1][srow][skc] = ra0;  *(uint4*)&As[cur ^ 1][srow + 64][skc] = ra1;
      *(uint4*)&Bs[cur ^ 1][srow][skc] = rb0;  *(uint4*)&Bs[cur ^ 1][srow + 64][skc] = rb1;
    }
    __syncthreads();
    cur ^= 1;
  }

  const size_t r0 = (size_t)bm * 128 + wr * 64;
  const int colbase = bn * 128 + wc * 64;
  float* Dz = D + (size_t)bz * 4096 * 256;
#pragma unroll
  for (int mi = 0; mi < 4; ++mi) {
    const size_t row = r0 + mi * 16 + fr;
#pragma unroll
    for (int nj = 0; nj < 4; ++nj) {
      const f32x4 v = acc[mi][nj];
      *(float4*)(Dz + row * 256 + colbase + nj * 16 + hi * 4) =
          make_float4(v[0], v[1], v[2], v[3]);
    }
  }
}

// ---------------- ctx partials: per (b,h,chunk): sum_n exp(k[d,n])*v[e,n] ---------
// kv layout [65536][512]: k at cols 0..255, v at 256..511.
__global__ __launch_bounds__(256) void ctx_part_kernel(const unsigned short* __restrict__ kv,
                                                       float* __restrict__ part,
                                                       float* __restrict__ spart) {
  const int blk = blockIdx.x;
  const int bh = blk >> 4, chunk = blk & 15;
  const int b = bh >> 3, h = bh & 7;
  const int tid = threadIdx.x, d = tid & 31, g = tid >> 5;
  const unsigned short* kbase =
      kv + (size_t)b * 4096 * 512 + h * 32 + (size_t)chunk * 256 * 512;
  const unsigned short* vbase = kbase + 256;

  __shared__ float ek[64][36], vv[64][36];
  float a0 = 0.f, a1 = 0.f, a2 = 0.f, a3 = 0.f, ssum = 0.f;
  const int e0 = g * 4;
  const int sn = tid >> 2, sc = (tid & 3) * 8;
  const unsigned short* kp0 = kbase + (size_t)sn * 512 + sc;
  const unsigned short* vp0 = vbase + (size_t)sn * 512 + sc;
  uint4 kr = *(const uint4*)kp0;
  uint4 vr = *(const uint4*)vp0;
  for (int n0 = 0; n0 < 256; n0 += 64) {
    float kf[8], vf[8];
    bf8_to_f(kr, kf); bf8_to_f(vr, vf);
    uint4 krn = kr, vrn = vr;
    if (n0 + 64 < 256) {
      krn = *(const uint4*)(kp0 + (size_t)(n0 + 64) * 512);
      vrn = *(const uint4*)(vp0 + (size_t)(n0 + 64) * 512);
    }
#pragma unroll
    for (int j = 0; j < 8; ++j) { ek[sn][sc + j] = __expf(kf[j]); vv[sn][sc + j] = vf[j]; }
    __syncthreads();
#pragma unroll 8
    for (int i = 0; i < 64; ++i) {
      const float kd = ek[i][d];
      const float4 v4 = *(const float4*)&vv[i][e0];
      ssum += kd;
      a0 += kd * v4.x; a1 += kd * v4.y; a2 += kd * v4.z; a3 += kd * v4.w;
    }
    __syncthreads();
    kr = krn; vr = vrn;
  }
  float* pp = part + ((size_t)chunk * 128 + bh) * 1024 + d * 32 + e0;
  pp[0] = a0; pp[1] = a1; pp[2] = a2; pp[3] = a3;
  if (g == 0) spart[((size_t)chunk * 128 + bh) * 32 + d] = ssum;
}

// ---------------- ctx combine: ctx[d][e] = sum_c part / sum_c spart ---------------
__global__ __launch_bounds__(256) void ctx_combine_kernel(const float* __restrict__ part,
                                                          const float* __restrict__ spart,
                                                          float* __restrict__ ctx) {
  const int bh = blockIdx.x, tid = threadIdx.x;
  __shared__ float sinv[32];
  if (tid < 32) {
    float s = 0.f;
#pragma unroll
    for (int c = 0; c < NCHUNK; ++c) s += spart[((size_t)c * 128 + bh) * 32 + tid];
    sinv[tid] = 1.0f / s;
  }
  __syncthreads();
  float4 acc = make_float4(0.f, 0.f, 0.f, 0.f);
#pragma unroll
  for (int c = 0; c < NCHUNK; ++c) {
    const float4 p = *(const float4*)(part + ((size_t)c * 128 + bh) * 1024 + tid * 4);
    acc.x += p.x; acc.y += p.y; acc.z += p.z; acc.w += p.w;
  }
  const float si = sinv[tid >> 3];  // d = (tid*4)>>5
  float4* cp = (float4*)(ctx + (size_t)bh * 1024 + tid * 4);
  *cp = make_float4(acc.x * si, acc.y * si, acc.z * si, acc.w * si);
}

// ---------------- w2: W2T[b][c][(h,d)] = sum_e ctx[b,h,d,e] * woutT[c][(h,e)] -----
__global__ __launch_bounds__(256) void w2_kernel(const float* __restrict__ ctx,
                                                 const unsigned short* __restrict__ woutT,
                                                 unsigned short* __restrict__ W2T) {
  const int b = blockIdx.x >> 4, cg = blockIdx.x & 15;
  const int tid = threadIdx.x;
  __shared__ float cs[8 * 32 * 32];  // ctx[b]: 8 heads x 32d x 32e = 32 KB
  {
    const float4* src = (const float4*)(ctx + (size_t)b * 8192);
    float4* dst = (float4*)cs;
#pragma unroll
    for (int i = 0; i < 8; ++i) dst[tid + i * 256] = src[tid + i * 256];
  }
  __syncthreads();
  const int c = cg * 16 + (tid >> 4), chunk = tid & 15;
  const int h = chunk >> 1, d0 = (chunk & 1) * 16;
  float wf[32];
  {
    const uint4* wp = (const uint4*)(woutT + (size_t)c * 256 + h * 32);
    bf8_to_f(wp[0], wf + 0); bf8_to_f(wp[1], wf + 8);
    bf8_to_f(wp[2], wf + 16); bf8_to_f(wp[3], wf + 24);
  }
  unsigned short o[16];
#pragma unroll
  for (int dd = 0; dd < 16; ++dd) {
    const float* cp = cs + h * 1024 + (d0 + dd) * 32;
    float acc = 0.f;
#pragma unroll
    for (int e = 0; e < 32; ++e) acc += cp[e] * wf[e];
    o[dd] = f2bf(acc);
  }
  uint4* op = (uint4*)(W2T + ((size_t)b * 256 + c) * 256 + chunk * 16);
  op[0] = make_uint4((unsigned)o[0] | ((unsigned)o[1] << 16), (unsigned)o[2] | ((unsigned)o[3] << 16),
                     (unsigned)o[4] | ((unsigned)o[5] << 16), (unsigned)o[6] | ((unsigned)o[7] << 16));
  op[1] = make_uint4((unsigned)o[8] | ((unsigned)o[9] << 16), (unsigned)o[10] | ((unsigned)o[11] << 16),
                     (unsigned)o[12] | ((unsigned)o[13] << 16), (unsigned)o[14] | ((unsigned)o[15] << 16));
}

extern "C" void kernel_launch(void* const* d_in, const int* in_sizes, int n_in,
                              void* d_out, int out_size, void* d_ws, size_t ws_size,
                              hipStream_t stream) {
  const float* x     = (const float*)d_in[0];  // [16,64,64,256] = [65536][256]
  const float* wqkv  = (const float*)d_in[1];  // [256,768]
  const float* wout  = (const float*)d_in[2];  // [256,256]
  float* out = (float*)d_out;                  // [65536,256] fp32

  char* ws = (char*)d_ws;
  unsigned short* xb    = (unsigned short*)(ws);                 // 32 MB (dead after gemm_qkv)
  unsigned short* wqkvT = (unsigned short*)(ws + 33554432);      // 384 KB
  unsigned short* woutT = (unsigned short*)(ws + 33947648);      // 128 KB
  unsigned short* kv    = (unsigned short*)(ws + 34078720);      // 64 MB [65536][512]
  float*          ctx   = (float*)        (ws + 101187584);      // 512 KB [128][32][32]
  unsigned short* qs    = (unsigned short*)(ws + 101711872);     // 32 MB [65536][256]
  // reuse xb region (dead after gemm_qkv):
  float*          part  = (float*)(ws);                          // 8 MB [16][128][1024]
  float*          spart = (float*)(ws + 8388608);                // 256 KB [16][128][32]
  unsigned short* W2T   = (unsigned short*)(ws + 12582912);      // 2 MB [16][256][256]

  prep_kernel<<<2048 + 768 + 256, 256, 0, stream>>>(x, wqkv, wout, xb, wqkvT, woutT);
  // gemm1: 6 bn strips (q 0..1 -> softmax -> qs; k 2..3 / v 4..5 -> kv[.][512]).
  // 1D grid 3072, XCD-swizzled.
  gemm_qkv<<<3072, 256, 0, stream>>>(xb, wqkvT, kv, qs, 256);
  ctx_part_kernel<<<2048, 256, 0, stream>>>(kv, part, spart);
  ctx_combine_kernel<<<128, 256, 0, stream>>>(part, spart, ctx);
  w2_kernel<<<256, 256, 0, stream>>>(ctx, woutT, W2T);
  // gemm2: batched z=16, M=4096, N=256, K=256; 1D grid 1024, XCD-chunked (bn fast).
  gemm_out<<<1024, 256, 0, stream>>>(qs, W2T, out, 256);
}

// Round 20
// 154.749 us; speedup vs baseline: 1.4113x; 1.0109x over previous
//
#include <hip/hip_runtime.h>

using short8 = __attribute__((ext_vector_type(8))) short;
using f32x4  = __attribute__((ext_vector_type(4))) float;

#define SCALE_Q 0.17677669529663687f   // 32^-0.5
#define NCHUNK 16

__device__ __forceinline__ unsigned short f2bf(float f) {
  unsigned u = __float_as_uint(f);
  return (unsigned short)((u + 0x7FFFu + ((u >> 16) & 1u)) >> 16);  // RNE
}
__device__ __forceinline__ float bf2f(unsigned h) { return __uint_as_float(h << 16); }

__device__ __forceinline__ void bf8_to_f(uint4 r, float* o) {
  o[0] = bf2f(r.x & 0xffffu); o[1] = bf2f(r.x >> 16);
  o[2] = bf2f(r.y & 0xffffu); o[3] = bf2f(r.y >> 16);
  o[4] = bf2f(r.z & 0xffffu); o[5] = bf2f(r.z >> 16);
  o[6] = bf2f(r.w & 0xffffu); o[7] = bf2f(r.w >> 16);
}

// ---------------- prep: x fp32 -> bf16 (grid-stride); transpose-convert weights --
__global__ __launch_bounds__(256) void prep_kernel(
    const float* __restrict__ x, const float* __restrict__ wqkv, const float* __restrict__ wout,
    unsigned short* __restrict__ xb, unsigned short* __restrict__ wqkvT,
    unsigned short* __restrict__ woutT) {
  const int blk = blockIdx.x;
  if (blk < 2048) {
    size_t idx = (size_t)blk * 256 + threadIdx.x;
#pragma unroll
    for (int it = 0; it < 8; ++it, idx += 2048 * 256) {
      const float4 v = *(const float4*)(x + idx * 4);
      *(ushort4*)(xb + idx * 4) = make_ushort4(f2bf(v.x), f2bf(v.y), f2bf(v.z), f2bf(v.w));
    }
  } else if (blk < 2048 + 768) {
    const int n = blk - 2048, k = threadIdx.x;             // wqkvT[n][k] = wqkv[k][n]
    wqkvT[n * 256 + k] = f2bf(wqkv[(size_t)k * 768 + n]);
  } else {
    const int c = blk - 2048 - 768, f = threadIdx.x;       // woutT[c][f] = wout[f][c]
    woutT[c * 256 + f] = f2bf(wout[(size_t)f * 256 + c]);
  }
}

// ---------------- gemm_qkv: R14 dbuf + launch_bounds(256,4) (measured 59.6 us) ---
__global__ __launch_bounds__(256, 4) void gemm_qkv(
    const unsigned short* __restrict__ A, const unsigned short* __restrict__ BT,
    unsigned short* __restrict__ KV, unsigned short* __restrict__ QS, int K) {
  __shared__ unsigned short As[2][128][40];
  __shared__ unsigned short Bs[2][128][40];
  const int cpx = (int)gridDim.x >> 3;
  const int lin = ((int)blockIdx.x & 7) * cpx + ((int)blockIdx.x >> 3);
  const int bn = lin % 6, bm = lin / 6;
  const int tid = threadIdx.x, lane = tid & 63, wid = tid >> 6;
  const int wr = wid >> 1, wc = wid & 1;
  const int fr = lane & 15, hi = lane >> 4, fk = hi * 8;
  f32x4 acc[4][4] = {};
  const size_t abase = (size_t)bm * 128 * K;
  const size_t bbase = (size_t)bn * 128 * K;

  const int srow = tid >> 2, skc = (tid & 3) * 8;
  uint4 ra0, ra1, rb0, rb1;
  const unsigned short* Ap = A + abase + (size_t)srow * K + skc;
  const unsigned short* Bp = BT + bbase + (size_t)srow * K + skc;

  ra0 = *(const uint4*)(Ap);            ra1 = *(const uint4*)(Ap + (size_t)64 * K);
  rb0 = *(const uint4*)(Bp);            rb1 = *(const uint4*)(Bp + (size_t)64 * K);
  *(uint4*)&As[0][srow][skc] = ra0;     *(uint4*)&As[0][srow + 64][skc] = ra1;
  *(uint4*)&Bs[0][srow][skc] = rb0;     *(uint4*)&Bs[0][srow + 64][skc] = rb1;
  __syncthreads();

  const int ktiles = K >> 5;
  int cur = 0;
  for (int t = 0; t < ktiles; ++t) {
    if (t + 1 < ktiles) {
      const int kt = (t + 1) * 32;
      ra0 = *(const uint4*)(Ap + kt);     ra1 = *(const uint4*)(Ap + (size_t)64 * K + kt);
      rb0 = *(const uint4*)(Bp + kt);     rb1 = *(const uint4*)(Bp + (size_t)64 * K + kt);
    }
    short8 af[4], bfv[4];
#pragma unroll
    for (int i = 0; i < 4; ++i) {
      af[i]  = *(const short8*)&As[cur][wr * 64 + i * 16 + fr][fk];
      bfv[i] = *(const short8*)&Bs[cur][wc * 64 + i * 16 + fr][fk];
    }
#pragma unroll
    for (int mi = 0; mi < 4; ++mi)
#pragma unroll
      for (int nj = 0; nj < 4; ++nj)  // swapped operands
        acc[mi][nj] = __builtin_amdgcn_mfma_f32_16x16x32_bf16(bfv[nj], af[mi], acc[mi][nj], 0, 0, 0);
    if (t + 1 < ktiles) {
      *(uint4*)&As[cur ^ 1][srow][skc] = ra0;  *(uint4*)&As[cur ^ 1][srow + 64][skc] = ra1;
      *(uint4*)&Bs[cur ^ 1][srow][skc] = rb0;  *(uint4*)&Bs[cur ^ 1][srow + 64][skc] = rb1;
    }
    __syncthreads();
    cur ^= 1;
  }

  const size_t r0 = (size_t)bm * 128 + wr * 64;
  if (bn < 2) {
    const int c0 = bn * 128 + wc * 64;
#pragma unroll
    for (int mi = 0; mi < 4; ++mi) {
      const size_t row = r0 + mi * 16 + fr;
#pragma unroll
      for (int p = 0; p < 2; ++p) {
        const f32x4 a0 = acc[mi][2 * p], a1 = acc[mi][2 * p + 1];
        float mx = fmaxf(fmaxf(fmaxf(a0[0], a0[1]), fmaxf(a0[2], a0[3])),
                         fmaxf(fmaxf(a1[0], a1[1]), fmaxf(a1[2], a1[3])));
        mx = fmaxf(mx, __shfl_xor(mx, 16, 64));
        mx = fmaxf(mx, __shfl_xor(mx, 32, 64));
        float e0[4], e1[4], s = 0.f;
#pragma unroll
        for (int r = 0; r < 4; ++r) {
          e0[r] = __expf(a0[r] - mx); e1[r] = __expf(a1[r] - mx);
          s += e0[r] + e1[r];
        }
        s += __shfl_xor(s, 16, 64);
        s += __shfl_xor(s, 32, 64);
        const float inv = SCALE_Q / s;
        unsigned short* qp = QS + row * 256 + c0 + p * 32 + hi * 4;
        *(ushort4*)(qp)      = make_ushort4(f2bf(e0[0]*inv), f2bf(e0[1]*inv), f2bf(e0[2]*inv), f2bf(e0[3]*inv));
        *(ushort4*)(qp + 16) = make_ushort4(f2bf(e1[0]*inv), f2bf(e1[1]*inv), f2bf(e1[2]*inv), f2bf(e1[3]*inv));
      }
    }
    return;
  }
  const int colbase = (bn - 2) * 128 + wc * 64;   // kv row = 512 cols (k 0..255, v 256+)
#pragma unroll
  for (int mi = 0; mi < 4; ++mi) {
    const size_t row = r0 + mi * 16 + fr;
#pragma unroll
    for (int nj = 0; nj < 4; ++nj) {
      const int col0 = colbase + nj * 16 + hi * 4;
      const f32x4 v = acc[mi][nj];
      *(ushort4*)(KV + row * 512 + col0) =
          make_ushort4(f2bf(v[0]), f2bf(v[1]), f2bf(v[2]), f2bf(v[3]));
    }
  }
}

// ---------------- gemm_out: R16/R19 version ---------------------------------------
__global__ __launch_bounds__(256, 4) void gemm_out(
    const unsigned short* __restrict__ A, const unsigned short* __restrict__ BT,
    float* __restrict__ D, int K) {
  __shared__ unsigned short As[2][128][40];
  __shared__ unsigned short Bs[2][128][40];
  const int cpx = (int)gridDim.x >> 3;
  const int lin = ((int)blockIdx.x & 7) * cpx + ((int)blockIdx.x >> 3);
  const int bn = lin & 1, bm = (lin >> 1) & 31, bz = lin >> 6;
  const int tid = threadIdx.x, lane = tid & 63, wid = tid >> 6;
  const int wr = wid >> 1, wc = wid & 1;
  const int fr = lane & 15, hi = lane >> 4, fk = hi * 8;
  f32x4 acc[4][4] = {};
  const size_t abase = (size_t)bz * 4096 * 256 + (size_t)bm * 128 * K;
  const size_t bbase = (size_t)bz * 256 * 256 + (size_t)bn * 128 * K;

  const int srow = tid >> 2, skc = (tid & 3) * 8;
  uint4 ra0, ra1, rb0, rb1;
  const unsigned short* Ap = A + abase + (size_t)srow * K + skc;
  const unsigned short* Bp = BT + bbase + (size_t)srow * K + skc;

  ra0 = *(const uint4*)(Ap);            ra1 = *(const uint4*)(Ap + (size_t)64 * K);
  rb0 = *(const uint4*)(Bp);            rb1 = *(const uint4*)(Bp + (size_t)64 * K);
  *(uint4*)&As[0][srow][skc] = ra0;     *(uint4*)&As[0][srow + 64][skc] = ra1;
  *(uint4*)&Bs[0][srow][skc] = rb0;     *(uint4*)&Bs[0][srow + 64][skc] = rb1;
  __syncthreads();

  const int ktiles = K >> 5;
  int cur = 0;
  for (int t = 0; t < ktiles; ++t) {
    if (t + 1 < ktiles) {
      const int kt = (t + 1) * 32;
      ra0 = *(const uint4*)(Ap + kt);     ra1 = *(const uint4*)(Ap + (size_t)64 * K + kt);
      rb0 = *(const uint4*)(Bp + kt);     rb1 = *(const uint4*)(Bp + (size_t)64 * K + kt);
    }
    short8 af[4], bfv[4];
#pragma unroll
    for (int i = 0; i < 4; ++i) {
      af[i]  = *(const short8*)&As[cur][wr * 64 + i * 16 + fr][fk];
      bfv[i] = *(const short8*)&Bs[cur][wc * 64 + i * 16 + fr][fk];
    }
#pragma unroll
    for (int mi = 0; mi < 4; ++mi)
#pragma unroll
      for (int nj = 0; nj < 4; ++nj)
        acc[mi][nj] = __builtin_amdgcn_mfma_f32_16x16x32_bf16(bfv[nj], af[mi], acc[mi][nj], 0, 0, 0);
    if (t + 1 < ktiles) {
      *(uint4*)&As[cur ^ 1][srow][skc] = ra0;  *(uint4*)&As[cur ^ 1][srow + 64][skc] = ra1;
      *(uint4*)&Bs[cur ^ 1][srow][skc] = rb0;  *(uint4*)&Bs[cur ^ 1][srow + 64][skc] = rb1;
    }
    __syncthreads();
    cur ^= 1;
  }

  const size_t r0 = (size_t)bm * 128 + wr * 64;
  const int colbase = bn * 128 + wc * 64;
  float* Dz = D + (size_t)bz * 4096 * 256;
#pragma unroll
  for (int mi = 0; mi < 4; ++mi) {
    const size_t row = r0 + mi * 16 + fr;
#pragma unroll
    for (int nj = 0; nj < 4; ++nj) {
      const f32x4 v = acc[mi][nj];
      *(float4*)(Dz + row * 256 + colbase + nj * 16 + hi * 4) =
          make_float4(v[0], v[1], v[2], v[3]);
    }
  }
}

// ---------------- ctx partials (register-blocked 4x4): sum_n exp(k)*v -------------
// Thread (s = tid>>6, dg = (tid&63)>>3, eg = tid&7) computes the 4x4 tile
// [d = dg*4..+4) x [e = eg*4..+4) over its n-quarter (rows s*16..s*16+15 of each
// staged 64-row chunk): per row 2 x ds_read_b128 for 16 FMA (was 1 b32 + 1 b128
// for 4 FMA, over 4x the rows) -> 4x fewer LDS instructions. Cross-quarter
// reduction reuses the staging LDS (aliased after the final barrier).
__global__ __launch_bounds__(256) void ctx_part_kernel(const unsigned short* __restrict__ kv,
                                                       float* __restrict__ part,
                                                       float* __restrict__ spart) {
  const int blk = blockIdx.x;
  const int bh = blk >> 4, chunk = blk & 15;
  const int b = bh >> 3, h = bh & 7;
  const int tid = threadIdx.x;
  const int s = tid >> 6, tile = tid & 63, dg = tile >> 3, eg = tile & 7;

  __shared__ float smem[2 * 64 * 36];          // 18.4 KB: ek | vv, later red | sred
  float* ek = smem;                            // [64][36]
  float* vv = smem + 64 * 36;                  // [64][36]

  const unsigned short* kbase =
      kv + (size_t)b * 4096 * 512 + h * 32 + (size_t)chunk * 256 * 512;
  const unsigned short* vbase = kbase + 256;
  const int sn = tid >> 2, sc = (tid & 3) * 8;
  const unsigned short* kp0 = kbase + (size_t)sn * 512 + sc;
  const unsigned short* vp0 = vbase + (size_t)sn * 512 + sc;

  f32x4 acc[4] = {};      // rows d = dg*4+r, cols e = eg*4..+3
  f32x4 ssumv = {};       // per-d partial sums (eg==0 threads only)

  uint4 kr = *(const uint4*)kp0;
  uint4 vr = *(const uint4*)vp0;
  for (int n0 = 0; n0 < 256; n0 += 64) {
    float kf[8], vf[8];
    bf8_to_f(kr, kf); bf8_to_f(vr, vf);
    uint4 krn = kr, vrn = vr;
    if (n0 + 64 < 256) {   // prefetch next chunk under this one's compute
      krn = *(const uint4*)(kp0 + (size_t)(n0 + 64) * 512);
      vrn = *(const uint4*)(vp0 + (size_t)(n0 + 64) * 512);
    }
#pragma unroll
    for (int j = 0; j < 8; ++j) { ek[sn * 36 + sc + j] = __expf(kf[j]); vv[sn * 36 + sc + j] = vf[j]; }
    __syncthreads();
#pragma unroll
    for (int ii = 0; ii < 16; ++ii) {
      const int i = s * 16 + ii;
      const f32x4 ek4 = *(const f32x4*)&ek[i * 36 + dg * 4];   // 144 B row stride: 16B-aligned
      const f32x4 vv4 = *(const f32x4*)&vv[i * 36 + eg * 4];
      acc[0] += vv4 * ek4[0];
      acc[1] += vv4 * ek4[1];
      acc[2] += vv4 * ek4[2];
      acc[3] += vv4 * ek4[3];
      if (eg == 0) ssumv += ek4;
    }
    __syncthreads();
    kr = krn; vr = vrn;
  }

  // reduction across the 4 n-quarters; alias smem (all LDS reads above are done)
  float* red  = smem;            // [4][64][16] = 4096 floats
  float* sred = smem + 4096;     // [4][8][4]   = 128 floats (fits in 4608)
#pragma unroll
  for (int r = 0; r < 4; ++r) *(f32x4*)&red[((s * 64) + tile) * 16 + r * 4] = acc[r];
  if (eg == 0) *(f32x4*)&sred[(s * 8 + dg) * 4] = ssumv;
  __syncthreads();
  if (s == 0) {   // tid < 64: finalize the 16 outputs of tile (dg, eg)
#pragma unroll
    for (int r = 0; r < 4; ++r) {
      f32x4 a = *(const f32x4*)&red[tile * 16 + r * 4];
#pragma unroll
      for (int q = 1; q < 4; ++q) a += *(const f32x4*)&red[(q * 64 + tile) * 16 + r * 4];
      *(f32x4*)&part[((size_t)chunk * 128 + bh) * 1024 + (size_t)(dg * 4 + r) * 32 + eg * 4] = a;
    }
  }
  if (tid < 32) {  // d = tid: sum sred over quarters
    const int dgq = tid >> 2, j = tid & 3;
    float v = sred[(0 * 8 + dgq) * 4 + j] + sred[(1 * 8 + dgq) * 4 + j] +
              sred[(2 * 8 + dgq) * 4 + j] + sred[(3 * 8 + dgq) * 4 + j];
    spart[((size_t)chunk * 128 + bh) * 32 + tid] = v;
  }
}

// ---------------- ctx combine: ctx[d][e] = sum_c part / sum_c spart ---------------
__global__ __launch_bounds__(256) void ctx_combine_kernel(const float* __restrict__ part,
                                                          const float* __restrict__ spart,
                                                          float* __restrict__ ctx) {
  const int bh = blockIdx.x, tid = threadIdx.x;
  __shared__ float sinv[32];
  if (tid < 32) {
    float s = 0.f;
#pragma unroll
    for (int c = 0; c < NCHUNK; ++c) s += spart[((size_t)c * 128 + bh) * 32 + tid];
    sinv[tid] = 1.0f / s;
  }
  __syncthreads();
  float4 acc = make_float4(0.f, 0.f, 0.f, 0.f);
#pragma unroll
  for (int c = 0; c < NCHUNK; ++c) {
    const float4 p = *(const float4*)(part + ((size_t)c * 128 + bh) * 1024 + tid * 4);
    acc.x += p.x; acc.y += p.y; acc.z += p.z; acc.w += p.w;
  }
  const float si = sinv[tid >> 3];  // d = (tid*4)>>5
  float4* cp = (float4*)(ctx + (size_t)bh * 1024 + tid * 4);
  *cp = make_float4(acc.x * si, acc.y * si, acc.z * si, acc.w * si);
}

// ---------------- w2: W2T[b][c][(h,d)] = sum_e ctx[b,h,d,e] * woutT[c][(h,e)] -----
__global__ __launch_bounds__(256) void w2_kernel(const float* __restrict__ ctx,
                                                 const unsigned short* __restrict__ woutT,
                                                 unsigned short* __restrict__ W2T) {
  const int b = blockIdx.x >> 4, cg = blockIdx.x & 15;
  const int tid = threadIdx.x;
  __shared__ float cs[8 * 32 * 32];  // ctx[b]: 8 heads x 32d x 32e = 32 KB
  {
    const float4* src = (const float4*)(ctx + (size_t)b * 8192);
    float4* dst = (float4*)cs;
#pragma unroll
    for (int i = 0; i < 8; ++i) dst[tid + i * 256] = src[tid + i * 256];
  }
  __syncthreads();
  const int c = cg * 16 + (tid >> 4), chunk = tid & 15;
  const int h = chunk >> 1, d0 = (chunk & 1) * 16;
  float wf[32];
  {
    const uint4* wp = (const uint4*)(woutT + (size_t)c * 256 + h * 32);
    bf8_to_f(wp[0], wf + 0); bf8_to_f(wp[1], wf + 8);
    bf8_to_f(wp[2], wf + 16); bf8_to_f(wp[3], wf + 24);
  }
  unsigned short o[16];
#pragma unroll
  for (int dd = 0; dd < 16; ++dd) {
    const float* cp = cs + h * 1024 + (d0 + dd) * 32;
    float acc = 0.f;
#pragma unroll
    for (int e = 0; e < 32; ++e) acc += cp[e] * wf[e];
    o[dd] = f2bf(acc);
  }
  uint4* op = (uint4*)(W2T + ((size_t)b * 256 + c) * 256 + chunk * 16);
  op[0] = make_uint4((unsigned)o[0] | ((unsigned)o[1] << 16), (unsigned)o[2] | ((unsigned)o[3] << 16),
                     (unsigned)o[4] | ((unsigned)o[5] << 16), (unsigned)o[6] | ((unsigned)o[7] << 16));
  op[1] = make_uint4((unsigned)o[8] | ((unsigned)o[9] << 16), (unsigned)o[10] | ((unsigned)o[11] << 16),
                     (unsigned)o[12] | ((unsigned)o[13] << 16), (unsigned)o[14] | ((unsigned)o[15] << 16));
}

extern "C" void kernel_launch(void* const* d_in, const int* in_sizes, int n_in,
                              void* d_out, int out_size, void* d_ws, size_t ws_size,
                              hipStream_t stream) {
  const float* x     = (const float*)d_in[0];  // [16,64,64,256] = [65536][256]
  const float* wqkv  = (const float*)d_in[1];  // [256,768]
  const float* wout  = (const float*)d_in[2];  // [256,256]
  float* out = (float*)d_out;                  // [65536,256] fp32

  char* ws = (char*)d_ws;
  unsigned short* xb    = (unsigned short*)(ws);                 // 32 MB (dead after gemm_qkv)
  unsigned short* wqkvT = (unsigned short*)(ws + 33554432);      // 384 KB
  unsigned short* woutT = (unsigned short*)(ws + 33947648);      // 128 KB
  unsigned short* kv    = (unsigned short*)(ws + 34078720);      // 64 MB [65536][512]
  float*          ctx   = (float*)        (ws + 101187584);      // 512 KB [128][32][32]
  unsigned short* qs    = (unsigned short*)(ws + 101711872);     // 32 MB [65536][256]
  // reuse xb region (dead after gemm_qkv):
  float*          part  = (float*)(ws);                          // 8 MB [16][128][1024]
  float*          spart = (float*)(ws + 8388608);                // 256 KB [16][128][32]
  unsigned short* W2T   = (unsigned short*)(ws + 12582912);      // 2 MB [16][256][256]

  prep_kernel<<<2048 + 768 + 256, 256, 0, stream>>>(x, wqkv, wout, xb, wqkvT, woutT);
  gemm_qkv<<<3072, 256, 0, stream>>>(xb, wqkvT, kv, qs, 256);
  ctx_part_kernel<<<2048, 256, 0, stream>>>(kv, part, spart);
  ctx_combine_kernel<<<128, 256, 0, stream>>>(part, spart, ctx);
  w2_kernel<<<256, 256, 0, stream>>>(ctx, woutT, W2T);
  gemm_out<<<1024, 256, 0, stream>>>(qs, W2T, out, 256);
}

// Round 21
// 153.636 us; speedup vs baseline: 1.4216x; 1.0072x over previous
//
#include <hip/hip_runtime.h>

using short8 = __attribute__((ext_vector_type(8))) short;
using f32x4  = __attribute__((ext_vector_type(4))) float;

#define SCALE_Q 0.17677669529663687f   // 32^-0.5
#define NCHUNK 16

__device__ __forceinline__ unsigned short f2bf(float f) {
  unsigned u = __float_as_uint(f);
  return (unsigned short)((u + 0x7FFFu + ((u >> 16) & 1u)) >> 16);  // RNE
}
__device__ __forceinline__ float bf2f(unsigned h) { return __uint_as_float(h << 16); }

__device__ __forceinline__ void bf8_to_f(uint4 r, float* o) {
  o[0] = bf2f(r.x & 0xffffu); o[1] = bf2f(r.x >> 16);
  o[2] = bf2f(r.y & 0xffffu); o[3] = bf2f(r.y >> 16);
  o[4] = bf2f(r.z & 0xffffu); o[5] = bf2f(r.z >> 16);
  o[6] = bf2f(r.w & 0xffffu); o[7] = bf2f(r.w >> 16);
}

// async global->LDS, 16 B per lane; LDS dest = wave-uniform base + lane*16,
// global source is PER-LANE (scatter allowed).
__device__ __forceinline__ void gl_lds16(const unsigned short* g, unsigned short* l) {
  __builtin_amdgcn_global_load_lds(
      (const __attribute__((address_space(1))) void*)g,
      (__attribute__((address_space(3))) void*)l, 16, 0, 0);
}

// ---------------- prep: x fp32 -> bf16 (grid-stride); transpose-convert weights --
__global__ __launch_bounds__(256) void prep_kernel(
    const float* __restrict__ x, const float* __restrict__ wqkv, const float* __restrict__ wout,
    unsigned short* __restrict__ xb, unsigned short* __restrict__ wqkvT,
    unsigned short* __restrict__ woutT) {
  const int blk = blockIdx.x;
  if (blk < 2048) {
    size_t idx = (size_t)blk * 256 + threadIdx.x;
#pragma unroll
    for (int it = 0; it < 8; ++it, idx += 2048 * 256) {
      const float4 v = *(const float4*)(x + idx * 4);
      *(ushort4*)(xb + idx * 4) = make_ushort4(f2bf(v.x), f2bf(v.y), f2bf(v.z), f2bf(v.w));
    }
  } else if (blk < 2048 + 768) {
    const int n = blk - 2048, k = threadIdx.x;             // wqkvT[n][k] = wqkv[k][n]
    wqkvT[n * 256 + k] = f2bf(wqkv[(size_t)k * 768 + n]);
  } else {
    const int c = blk - 2048 - 768, f = threadIdx.x;       // woutT[c][f] = wout[f][c]
    woutT[c * 256 + f] = f2bf(wout[(size_t)f * 256 + c]);
  }
}

// ---------------- gemm_qkv: R14 dbuf pipeline + global_load_lds staging ----------
// qkv = xb[65536][256] * wqkvT[768][256]^T. 128x128 tile, BK=32, LINEAR LDS x2
// (16 KB/buf), 4 waves (2x2), 4x4 frags of 16x16x32, rolled loop.
// Staging via global_load_lds width-16 (async DMA, no VGPR round-trip). Both-sides
// chunk swizzle (rule 21): LDS[row][c] holds A[row][c ^ (row&3)] (16B chunks, 4 per
// 64B row) via pre-swizzled per-lane GLOBAL source; ds_read uses chunk hi^(fr&3)
// -> 4-way max bank aliasing. Pipeline per iter:
//   issue 4 glds(t+1 -> buf^1) -> ds_read+MFMA(t, buf cur) -> barrier (drains vmcnt).
// MFMA operands SWAPPED (R8-verified): lane (fr,hi) reg r holds
// D[r0 + mi*16 + fr][cb + nj*16 + hi*4 + r] -> packed stores, 2-shfl q-softmax.
// Bijective XCD chunk remap: same-bm strips co-XCD (FETCH ~18 MB).
// bn 0..1 -> fused q-softmax into QS; bn 2..3 -> k, bn 4..5 -> v into KV[.][512].
__global__ __launch_bounds__(256, 4) void gemm_qkv(
    const unsigned short* __restrict__ A, const unsigned short* __restrict__ BT,
    unsigned short* __restrict__ KV, unsigned short* __restrict__ QS, int K) {
  __shared__ __align__(16) unsigned short As[2][128 * 32];
  __shared__ __align__(16) unsigned short Bs[2][128 * 32];
  const int cpx = (int)gridDim.x >> 3;
  const int lin = ((int)blockIdx.x & 7) * cpx + ((int)blockIdx.x >> 3);
  const int bn = lin % 6, bm = lin / 6;
  const int tid = threadIdx.x, lane = tid & 63, wid = tid >> 6;
  const int wr = wid >> 1, wc = wid & 1;
  const int fr = lane & 15, hi = lane >> 4;
  f32x4 acc[4][4] = {};
  const size_t abase = (size_t)bm * 128 * K;
  const size_t bbase = (size_t)bn * 128 * K;

  // staging source (per-lane, pre-swizzled): issue i covers rows (i*4+wid)*16..+16;
  // lane l -> row +(l>>2), global chunk (l&3) ^ ((l>>2)&3)  (row&3 == (l>>2)&3)
  const int r_off = lane >> 2;
  const int schunk = (lane & 3) ^ (r_off & 3);
  const unsigned short* ApA0 = A + abase + (size_t)(wid * 16 + r_off) * K + schunk * 8;
  const unsigned short* ApA1 = ApA0 + (size_t)64 * K;
  const unsigned short* ApB0 = BT + bbase + (size_t)(wid * 16 + r_off) * K + schunk * 8;
  const unsigned short* ApB1 = ApB0 + (size_t)64 * K;
  // LDS dest bases (wave-uniform): issue i -> shorts (i*4+wid)*512
  const int d0 = wid * 512, d1 = (4 + wid) * 512;

  // prologue: tile 0 -> buf 0
  gl_lds16(ApA0, &As[0][d0]);  gl_lds16(ApA1, &As[0][d1]);
  gl_lds16(ApB0, &Bs[0][d0]);  gl_lds16(ApB1, &Bs[0][d1]);
  __syncthreads();

  // read-side swizzled chunk: hi ^ (fr & 3)
  const int rchunk = (hi ^ (fr & 3)) * 8;
  const int ktiles = K >> 5;
  int cur = 0;
  for (int t = 0; t < ktiles; ++t) {
    if (t + 1 < ktiles) {                 // async DMA next tile into buf^1
      const int kt = (t + 1) * 32;
      gl_lds16(ApA0 + kt, &As[cur ^ 1][d0]);  gl_lds16(ApA1 + kt, &As[cur ^ 1][d1]);
      gl_lds16(ApB0 + kt, &Bs[cur ^ 1][d0]);  gl_lds16(ApB1 + kt, &Bs[cur ^ 1][d1]);
    }
    short8 af[4], bfv[4];
#pragma unroll
    for (int i = 0; i < 4; ++i) {
      af[i]  = *(const short8*)&As[cur][(wr * 64 + i * 16 + fr) * 32 + rchunk];
      bfv[i] = *(const short8*)&Bs[cur][(wc * 64 + i * 16 + fr) * 32 + rchunk];
    }
#pragma unroll
    for (int mi = 0; mi < 4; ++mi)
#pragma unroll
      for (int nj = 0; nj < 4; ++nj)  // swapped operands
        acc[mi][nj] = __builtin_amdgcn_mfma_f32_16x16x32_bf16(bfv[nj], af[mi], acc[mi][nj], 0, 0, 0);
    __syncthreads();                      // drains vmcnt -> tile t+1 landed
    cur ^= 1;
  }

  const size_t r0 = (size_t)bm * 128 + wr * 64;
  if (bn < 2) {
    // q strips: per (row, head p) softmax over d=32. Lane holds 8 of the 32
    // d-values; reduce across hi groups with 2 shfl_xor (16, 32).
    const int c0 = bn * 128 + wc * 64;
#pragma unroll
    for (int mi = 0; mi < 4; ++mi) {
      const size_t row = r0 + mi * 16 + fr;
#pragma unroll
      for (int p = 0; p < 2; ++p) {
        const f32x4 a0 = acc[mi][2 * p], a1 = acc[mi][2 * p + 1];
        float mx = fmaxf(fmaxf(fmaxf(a0[0], a0[1]), fmaxf(a0[2], a0[3])),
                         fmaxf(fmaxf(a1[0], a1[1]), fmaxf(a1[2], a1[3])));
        mx = fmaxf(mx, __shfl_xor(mx, 16, 64));
        mx = fmaxf(mx, __shfl_xor(mx, 32, 64));
        float e0[4], e1[4], s = 0.f;
#pragma unroll
        for (int r = 0; r < 4; ++r) {
          e0[r] = __expf(a0[r] - mx); e1[r] = __expf(a1[r] - mx);
          s += e0[r] + e1[r];
        }
        s += __shfl_xor(s, 16, 64);
        s += __shfl_xor(s, 32, 64);
        const float inv = SCALE_Q / s;
        unsigned short* qp = QS + row * 256 + c0 + p * 32 + hi * 4;
        *(ushort4*)(qp)      = make_ushort4(f2bf(e0[0]*inv), f2bf(e0[1]*inv), f2bf(e0[2]*inv), f2bf(e0[3]*inv));
        *(ushort4*)(qp + 16) = make_ushort4(f2bf(e1[0]*inv), f2bf(e1[1]*inv), f2bf(e1[2]*inv), f2bf(e1[3]*inv));
      }
    }
    return;
  }
  const int colbase = (bn - 2) * 128 + wc * 64;   // kv row = 512 cols (k 0..255, v 256+)
#pragma unroll
  for (int mi = 0; mi < 4; ++mi) {
    const size_t row = r0 + mi * 16 + fr;
#pragma unroll
    for (int nj = 0; nj < 4; ++nj) {
      const int col0 = colbase + nj * 16 + hi * 4;
      const f32x4 v = acc[mi][nj];
      *(ushort4*)(KV + row * 512 + col0) =
          make_ushort4(f2bf(v[0]), f2bf(v[1]), f2bf(v[2]), f2bf(v[3]));
    }
  }
}

// ---------------- gemm_out: R16/R19 version (control — unchanged) -----------------
__global__ __launch_bounds__(256, 4) void gemm_out(
    const unsigned short* __restrict__ A, const unsigned short* __restrict__ BT,
    float* __restrict__ D, int K) {
  __shared__ unsigned short As[2][128][40];
  __shared__ unsigned short Bs[2][128][40];
  const int cpx = (int)gridDim.x >> 3;
  const int lin = ((int)blockIdx.x & 7) * cpx + ((int)blockIdx.x >> 3);
  const int bn = lin & 1, bm = (lin >> 1) & 31, bz = lin >> 6;
  const int tid = threadIdx.x, lane = tid & 63, wid = tid >> 6;
  const int wr = wid >> 1, wc = wid & 1;
  const int fr = lane & 15, hi = lane >> 4, fk = hi * 8;
  f32x4 acc[4][4] = {};
  const size_t abase = (size_t)bz * 4096 * 256 + (size_t)bm * 128 * K;
  const size_t bbase = (size_t)bz * 256 * 256 + (size_t)bn * 128 * K;

  const int srow = tid >> 2, skc = (tid & 3) * 8;
  uint4 ra0, ra1, rb0, rb1;
  const unsigned short* Ap = A + abase + (size_t)srow * K + skc;
  const unsigned short* Bp = BT + bbase + (size_t)srow * K + skc;

  ra0 = *(const uint4*)(Ap);            ra1 = *(const uint4*)(Ap + (size_t)64 * K);
  rb0 = *(const uint4*)(Bp);            rb1 = *(const uint4*)(Bp + (size_t)64 * K);
  *(uint4*)&As[0][srow][skc] = ra0;     *(uint4*)&As[0][srow + 64][skc] = ra1;
  *(uint4*)&Bs[0][srow][skc] = rb0;     *(uint4*)&Bs[0][srow + 64][skc] = rb1;
  __syncthreads();

  const int ktiles = K >> 5;
  int cur = 0;
  for (int t = 0; t < ktiles; ++t) {
    if (t + 1 < ktiles) {
      const int kt = (t + 1) * 32;
      ra0 = *(const uint4*)(Ap + kt);     ra1 = *(const uint4*)(Ap + (size_t)64 * K + kt);
      rb0 = *(const uint4*)(Bp + kt);     rb1 = *(const uint4*)(Bp + (size_t)64 * K + kt);
    }
    short8 af[4], bfv[4];
#pragma unroll
    for (int i = 0; i < 4; ++i) {
      af[i]  = *(const short8*)&As[cur][wr * 64 + i * 16 + fr][fk];
      bfv[i] = *(const short8*)&Bs[cur][wc * 64 + i * 16 + fr][fk];
    }
#pragma unroll
    for (int mi = 0; mi < 4; ++mi)
#pragma unroll
      for (int nj = 0; nj < 4; ++nj)
        acc[mi][nj] = __builtin_amdgcn_mfma_f32_16x16x32_bf16(bfv[nj], af[mi], acc[mi][nj], 0, 0, 0);
    if (t + 1 < ktiles) {
      *(uint4*)&As[cur ^ 1][srow][skc] = ra0;  *(uint4*)&As[cur ^ 1][srow + 64][skc] = ra1;
      *(uint4*)&Bs[cur ^ 1][srow][skc] = rb0;  *(uint4*)&Bs[cur ^ 1][srow + 64][skc] = rb1;
    }
    __syncthreads();
    cur ^= 1;
  }

  const size_t r0 = (size_t)bm * 128 + wr * 64;
  const int colbase = bn * 128 + wc * 64;
  float* Dz = D + (size_t)bz * 4096 * 256;
#pragma unroll
  for (int mi = 0; mi < 4; ++mi) {
    const size_t row = r0 + mi * 16 + fr;
#pragma unroll
    for (int nj = 0; nj < 4; ++nj) {
      const f32x4 v = acc[mi][nj];
      *(float4*)(Dz + row * 256 + colbase + nj * 16 + hi * 4) =
          make_float4(v[0], v[1], v[2], v[3]);
    }
  }
}

// ---------------- ctx partials (register-blocked 4x4): sum_n exp(k)*v -------------
__global__ __launch_bounds__(256) void ctx_part_kernel(const unsigned short* __restrict__ kv,
                                                       float* __restrict__ part,
                                                       float* __restrict__ spart) {
  const int blk = blockIdx.x;
  const int bh = blk >> 4, chunk = blk & 15;
  const int b = bh >> 3, h = bh & 7;
  const int tid = threadIdx.x;
  const int s = tid >> 6, tile = tid & 63, dg = tile >> 3, eg = tile & 7;

  __shared__ float smem[2 * 64 * 36];          // 18.4 KB: ek | vv, later red | sred
  float* ek = smem;                            // [64][36]
  float* vv = smem + 64 * 36;                  // [64][36]

  const unsigned short* kbase =
      kv + (size_t)b * 4096 * 512 + h * 32 + (size_t)chunk * 256 * 512;
  const unsigned short* vbase = kbase + 256;
  const int sn = tid >> 2, sc = (tid & 3) * 8;
  const unsigned short* kp0 = kbase + (size_t)sn * 512 + sc;
  const unsigned short* vp0 = vbase + (size_t)sn * 512 + sc;

  f32x4 acc[4] = {};
  f32x4 ssumv = {};

  uint4 kr = *(const uint4*)kp0;
  uint4 vr = *(const uint4*)vp0;
  for (int n0 = 0; n0 < 256; n0 += 64) {
    float kf[8], vf[8];
    bf8_to_f(kr, kf); bf8_to_f(vr, vf);
    uint4 krn = kr, vrn = vr;
    if (n0 + 64 < 256) {
      krn = *(const uint4*)(kp0 + (size_t)(n0 + 64) * 512);
      vrn = *(const uint4*)(vp0 + (size_t)(n0 + 64) * 512);
    }
#pragma unroll
    for (int j = 0; j < 8; ++j) { ek[sn * 36 + sc + j] = __expf(kf[j]); vv[sn * 36 + sc + j] = vf[j]; }
    __syncthreads();
#pragma unroll
    for (int ii = 0; ii < 16; ++ii) {
      const int i = s * 16 + ii;
      const f32x4 ek4 = *(const f32x4*)&ek[i * 36 + dg * 4];
      const f32x4 vv4 = *(const f32x4*)&vv[i * 36 + eg * 4];
      acc[0] += vv4 * ek4[0];
      acc[1] += vv4 * ek4[1];
      acc[2] += vv4 * ek4[2];
      acc[3] += vv4 * ek4[3];
      if (eg == 0) ssumv += ek4;
    }
    __syncthreads();
    kr = krn; vr = vrn;
  }

  float* red  = smem;            // [4][64][16]
  float* sred = smem + 4096;     // [4][8][4]
#pragma unroll
  for (int r = 0; r < 4; ++r) *(f32x4*)&red[((s * 64) + tile) * 16 + r * 4] = acc[r];
  if (eg == 0) *(f32x4*)&sred[(s * 8 + dg) * 4] = ssumv;
  __syncthreads();
  if (s == 0) {
#pragma unroll
    for (int r = 0; r < 4; ++r) {
      f32x4 a = *(const f32x4*)&red[tile * 16 + r * 4];
#pragma unroll
      for (int q = 1; q < 4; ++q) a += *(const f32x4*)&red[(q * 64 + tile) * 16 + r * 4];
      *(f32x4*)&part[((size_t)chunk * 128 + bh) * 1024 + (size_t)(dg * 4 + r) * 32 + eg * 4] = a;
    }
  }
  if (tid < 32) {
    const int dgq = tid >> 2, j = tid & 3;
    float v = sred[(0 * 8 + dgq) * 4 + j] + sred[(1 * 8 + dgq) * 4 + j] +
              sred[(2 * 8 + dgq) * 4 + j] + sred[(3 * 8 + dgq) * 4 + j];
    spart[((size_t)chunk * 128 + bh) * 32 + tid] = v;
  }
}

// ---------------- ctx combine: ctx[d][e] = sum_c part / sum_c spart ---------------
__global__ __launch_bounds__(256) void ctx_combine_kernel(const float* __restrict__ part,
                                                          const float* __restrict__ spart,
                                                          float* __restrict__ ctx) {
  const int bh = blockIdx.x, tid = threadIdx.x;
  __shared__ float sinv[32];
  if (tid < 32) {
    float s = 0.f;
#pragma unroll
    for (int c = 0; c < NCHUNK; ++c) s += spart[((size_t)c * 128 + bh) * 32 + tid];
    sinv[tid] = 1.0f / s;
  }
  __syncthreads();
  float4 acc = make_float4(0.f, 0.f, 0.f, 0.f);
#pragma unroll
  for (int c = 0; c < NCHUNK; ++c) {
    const float4 p = *(const float4*)(part + ((size_t)c * 128 + bh) * 1024 + tid * 4);
    acc.x += p.x; acc.y += p.y; acc.z += p.z; acc.w += p.w;
  }
  const float si = sinv[tid >> 3];  // d = (tid*4)>>5
  float4* cp = (float4*)(ctx + (size_t)bh * 1024 + tid * 4);
  *cp = make_float4(acc.x * si, acc.y * si, acc.z * si, acc.w * si);
}

// ---------------- w2: W2T[b][c][(h,d)] = sum_e ctx[b,h,d,e] * woutT[c][(h,e)] -----
__global__ __launch_bounds__(256) void w2_kernel(const float* __restrict__ ctx,
                                                 const unsigned short* __restrict__ woutT,
                                                 unsigned short* __restrict__ W2T) {
  const int b = blockIdx.x >> 4, cg = blockIdx.x & 15;
  const int tid = threadIdx.x;
  __shared__ float cs[8 * 32 * 32];  // ctx[b]: 8 heads x 32d x 32e = 32 KB
  {
    const float4* src = (const float4*)(ctx + (size_t)b * 8192);
    float4* dst = (float4*)cs;
#pragma unroll
    for (int i = 0; i < 8; ++i) dst[tid + i * 256] = src[tid + i * 256];
  }
  __syncthreads();
  const int c = cg * 16 + (tid >> 4), chunk = tid & 15;
  const int h = chunk >> 1, d0 = (chunk & 1) * 16;
  float wf[32];
  {
    const uint4* wp = (const uint4*)(woutT + (size_t)c * 256 + h * 32);
    bf8_to_f(wp[0], wf + 0); bf8_to_f(wp[1], wf + 8);
    bf8_to_f(wp[2], wf + 16); bf8_to_f(wp[3], wf + 24);
  }
  unsigned short o[16];
#pragma unroll
  for (int dd = 0; dd < 16; ++dd) {
    const float* cp = cs + h * 1024 + (d0 + dd) * 32;
    float acc = 0.f;
#pragma unroll
    for (int e = 0; e < 32; ++e) acc += cp[e] * wf[e];
    o[dd] = f2bf(acc);
  }
  uint4* op = (uint4*)(W2T + ((size_t)b * 256 + c) * 256 + chunk * 16);
  op[0] = make_uint4((unsigned)o[0] | ((unsigned)o[1] << 16), (unsigned)o[2] | ((unsigned)o[3] << 16),
                     (unsigned)o[4] | ((unsigned)o[5] << 16), (unsigned)o[6] | ((unsigned)o[7] << 16));
  op[1] = make_uint4((unsigned)o[8] | ((unsigned)o[9] << 16), (unsigned)o[10] | ((unsigned)o[11] << 16),
                     (unsigned)o[12] | ((unsigned)o[13] << 16), (unsigned)o[14] | ((unsigned)o[15] << 16));
}

extern "C" void kernel_launch(void* const* d_in, const int* in_sizes, int n_in,
                              void* d_out, int out_size, void* d_ws, size_t ws_size,
                              hipStream_t stream) {
  const float* x     = (const float*)d_in[0];  // [16,64,64,256] = [65536][256]
  const float* wqkv  = (const float*)d_in[1];  // [256,768]
  const float* wout  = (const float*)d_in[2];  // [256,256]
  float* out = (float*)d_out;                  // [65536,256] fp32

  char* ws = (char*)d_ws;
  unsigned short* xb    = (unsigned short*)(ws);                 // 32 MB (dead after gemm_qkv)
  unsigned short* wqkvT = (unsigned short*)(ws + 33554432);      // 384 KB
  unsigned short* woutT = (unsigned short*)(ws + 33947648);      // 128 KB
  unsigned short* kv    = (unsigned short*)(ws + 34078720);      // 64 MB [65536][512]
  float*          ctx   = (float*)        (ws + 101187584);      // 512 KB [128][32][32]
  unsigned short* qs    = (unsigned short*)(ws + 101711872);     // 32 MB [65536][256]
  // reuse xb region (dead after gemm_qkv):
  float*          part  = (float*)(ws);                          // 8 MB [16][128][1024]
  float*          spart = (float*)(ws + 8388608);                // 256 KB [16][128][32]
  unsigned short* W2T   = (unsigned short*)(ws + 12582912);      // 2 MB [16][256][256]

  prep_kernel<<<2048 + 768 + 256, 256, 0, stream>>>(x, wqkv, wout, xb, wqkvT, woutT);
  gemm_qkv<<<3072, 256, 0, stream>>>(xb, wqkvT, kv, qs, 256);
  ctx_part_kernel<<<2048, 256, 0, stream>>>(kv, part, spart);
  ctx_combine_kernel<<<128, 256, 0, stream>>>(part, spart, ctx);
  w2_kernel<<<256, 256, 0, stream>>>(ctx, woutT, W2T);
  gemm_out<<<1024, 256, 0, stream>>>(qs, W2T, out, 256);
}